// Round 1
// baseline (651.649 us; speedup 1.0000x reference)
//
#include <hip/hip_runtime.h>
#include <math.h>

#define BB 2048
#define LL 120
#define WE_ 50
#define PE_ 5
#define DD 60
#define FF 230
#define KK 3
#define RR 53

__global__ __launch_bounds__(256, 2) void pcnn_fused(
    const int* __restrict__ sent, const int* __restrict__ pf,
    const int* __restrict__ epos,
    const float* __restrict__ Wword, const float* __restrict__ Wpos1,
    const float* __restrict__ Wpos2,
    const float* __restrict__ convw, const float* __restrict__ convb,
    const float* __restrict__ linw, const float* __restrict__ linb,
    float* __restrict__ out)
{
    __shared__ float emb[(LL + 2) * DD];   // row l+1 holds emb[b,l,:]; rows 0 and L+1 are zero pad
    __shared__ float feats[FF * 3];

    const int b = blockIdx.x;
    const int tid = threadIdx.x;

    // zero the two padding rows
    for (int i = tid; i < 2 * DD; i += 256) {
        int r = (i < DD) ? 0 : (LL + 1);
        emb[r * DD + (i % DD)] = 0.0f;
    }
    // word embeddings: emb[l+1][0..49]
    for (int i = tid; i < LL * WE_; i += 256) {
        int l = i / WE_;
        int d = i - l * WE_;
        int w = sent[b * LL + l];
        emb[(l + 1) * DD + d] = Wword[w * WE_ + d];
    }
    // position embeddings: emb[l+1][50..54], emb[l+1][55..59]
    for (int i = tid; i < LL * PE_; i += 256) {
        int l = i / PE_;
        int d = i - l * PE_;
        int p = pf[(b * 2 + 0) * LL + l];
        int q = pf[(b * 2 + 1) * LL + l];
        emb[(l + 1) * DD + WE_ + d]       = Wpos1[p * PE_ + d];
        emb[(l + 1) * DD + WE_ + PE_ + d] = Wpos2[q * PE_ + d];
    }
    __syncthreads();

    const int pool0 = epos[b * 2 + 0] + 1;
    const int pool1 = epos[b * 2 + 1] + 1;

    const int f = tid;
    if (f < FF) {
        // filter fully resident in VGPRs (all indices compile-time after unroll)
        float w[KK * DD];
        #pragma unroll
        for (int i = 0; i < KK * DD; ++i) w[i] = convw[f * (KK * DD) + i];
        const float bias = convb[f];

        float m0 = -INFINITY, m1 = -INFINITY, m2 = -INFINITY;
        const float4* e4 = (const float4*)emb;

        for (int l = 0; l < LL; ++l) {
            float acc = bias;
            #pragma unroll
            for (int k = 0; k < KK; ++k) {
                #pragma unroll
                for (int d4 = 0; d4 < DD / 4; ++d4) {
                    // all lanes read the SAME LDS address -> broadcast, conflict-free
                    float4 e = e4[(l + k) * (DD / 4) + d4];
                    acc += e.x * w[k * DD + d4 * 4 + 0];
                    acc += e.y * w[k * DD + d4 * 4 + 1];
                    acc += e.z * w[k * DD + d4 * 4 + 2];
                    acc += e.w * w[k * DD + d4 * 4 + 3];
                }
            }
            float y = tanhf(acc);
            int seg = (l >= pool0) + (l >= pool1);  // wave-uniform
            if (seg == 0)      m0 = fmaxf(m0, y);
            else if (seg == 1) m1 = fmaxf(m1, y);
            else               m2 = fmaxf(m2, y);
        }
        feats[f * 3 + 0] = m0;
        feats[f * 3 + 1] = m1;
        feats[f * 3 + 2] = m2;
    }
    __syncthreads();

    // epilogue: out[b, r] = feats . lin_w[r, :] + lin_b[r]
    if (tid < RR) {
        float acc = linb[tid];
        #pragma unroll 6
        for (int i = 0; i < 3 * FF; ++i) {
            acc += feats[i] * linw[tid * (3 * FF) + i];
        }
        out[b * RR + tid] = acc;
    }
}

extern "C" void kernel_launch(void* const* d_in, const int* in_sizes, int n_in,
                              void* d_out, int out_size, void* d_ws, size_t ws_size,
                              hipStream_t stream) {
    const int*   sent  = (const int*)d_in[0];
    const int*   pf    = (const int*)d_in[1];
    const int*   epos  = (const int*)d_in[2];
    const float* Wword = (const float*)d_in[3];
    const float* Wpos1 = (const float*)d_in[4];
    const float* Wpos2 = (const float*)d_in[5];
    const float* convw = (const float*)d_in[6];
    const float* convb = (const float*)d_in[7];
    const float* linw  = (const float*)d_in[8];
    const float* linb  = (const float*)d_in[9];
    float* out = (float*)d_out;

    pcnn_fused<<<BB, 256, 0, stream>>>(sent, pf, epos, Wword, Wpos1, Wpos2,
                                       convw, convb, linw, linb, out);
}

// Round 3
// 216.657 us; speedup vs baseline: 3.0077x; 3.0077x over previous
//
#include <hip/hip_runtime.h>
#include <math.h>

#define BB 2048
#define LL 120
#define WE_ 50
#define PE_ 5
#define DD 60
#define FF 230
#define KK 3
#define RR 53

#define KPAD 192          // 6 k-tiles of 32
#define NPAD 240          // 15 n-tiles of 16
#define NKT 6
#define NNT 15
#define EMB_ELEMS 7936    // >= 127*60 + 192 = 7812; rows 0, >=121 and tail zeroed

typedef __attribute__((ext_vector_type(8))) short short8_t;
typedef __attribute__((ext_vector_type(4))) short short4_t;
typedef __attribute__((ext_vector_type(4))) float float4_t;

__device__ __forceinline__ unsigned short f2bf(float x) {
    unsigned u = __builtin_bit_cast(unsigned, x);
    unsigned r = (u + 0x7fffu + ((u >> 16) & 1u)) >> 16;
    return (unsigned short)r;
}

__device__ __forceinline__ float tanh_fast(float x) {
    // tanh(x) = 1 - 2/(e^{2x}+1); __expf -> v_exp_f32, rcp -> v_rcp_f32
    float t = __expf(2.0f * x);
    return 1.0f - 2.0f * __builtin_amdgcn_rcpf(t + 1.0f);
}

// ---- prep: pack conv_w (f32 [230][180]) into bf16 MFMA B-fragment-linear layout ----
// Bp element idx = (((nt*6 + kt)*64) + lane)*8 + j  maps to
// W[f = nt*16 + (lane&15)][klin = kt*32 + (lane>>4)*8 + j]
__global__ __launch_bounds__(256) void pcnn_prep_b(const float* __restrict__ convw,
                                                   unsigned short* __restrict__ bp) {
    int idx = blockIdx.x * 256 + threadIdx.x;
    if (idx >= NNT * NKT * 64 * 8) return;
    int j    = idx & 7;
    int lane = (idx >> 3) & 63;
    int t    = idx >> 9;
    int kt   = t % NKT;
    int nt   = t / NKT;
    int f    = nt * 16 + (lane & 15);
    int klin = kt * 32 + (lane >> 4) * 8 + j;
    float v = (f < FF && klin < KK * DD) ? convw[f * (KK * DD) + klin] : 0.0f;
    bp[idx] = f2bf(v);
}

__global__ __launch_bounds__(256) void pcnn_mfma(
    const int* __restrict__ sent, const int* __restrict__ pf,
    const int* __restrict__ epos,
    const float* __restrict__ Wword, const float* __restrict__ Wpos1,
    const float* __restrict__ Wpos2,
    const unsigned short* __restrict__ bp, const float* __restrict__ convb,
    const float* __restrict__ linw, const float* __restrict__ linb,
    float* __restrict__ out)
{
    __shared__ unsigned short emb[EMB_ELEMS];       // bf16, row stride 60, row p = l (A row l reads emb[l*60..])
    __shared__ float partial[4 * NPAD * 3];         // per-wave segment maxima, [wid][f][s]
    __shared__ float feats[NPAD * 3];

    const int b    = blockIdx.x;
    const int tid  = threadIdx.x;
    const int wid  = tid >> 6;
    const int lane = tid & 63;

    // ---- zero pad regions: row 0 -> [0,60) and tail [7260, EMB_ELEMS) ----
    for (int i = tid; i < 60 + (EMB_ELEMS - 7260); i += 256) {
        int idx = (i < 60) ? i : (7260 + (i - 60));
        emb[idx] = 0;
    }
    // ---- gather word embeddings: emb[(l+1)*60 + d], d<50 ----
    for (int i = tid; i < LL * WE_; i += 256) {
        int l = i / WE_;
        int d = i - l * WE_;
        int w = sent[b * LL + l];
        emb[(l + 1) * DD + d] = f2bf(Wword[w * WE_ + d]);
    }
    // ---- gather position embeddings: emb[(l+1)*60 + 50..59] ----
    for (int i = tid; i < LL * 2 * PE_; i += 256) {
        int l = i / (2 * PE_);
        int d = i - l * (2 * PE_);
        if (d < PE_) {
            int p = pf[b * 2 * LL + l];
            emb[(l + 1) * DD + WE_ + d] = f2bf(Wpos1[p * PE_ + d]);
        } else {
            int q = pf[b * 2 * LL + LL + l];
            emb[(l + 1) * DD + WE_ + d] = f2bf(Wpos2[q * PE_ + (d - PE_)]);
        }
    }
    __syncthreads();

    const int pool0 = epos[b * 2 + 0] + 1;
    const int pool1 = epos[b * 2 + 1] + 1;

    // ---- load A fragments: wave owns m-tiles {2*wid, 2*wid+1} ----
    // im2col row l = emb[l*60 .. l*60+180); frag: m = lane&15, k = (lane>>4)*8 + j
    short8_t afrag[2][NKT];
    #pragma unroll
    for (int tm2 = 0; tm2 < 2; ++tm2) {
        int l = (2 * wid + tm2) * 16 + (lane & 15);
        #pragma unroll
        for (int kt = 0; kt < NKT; ++kt) {
            int e = l * DD + kt * 32 + (lane >> 4) * 8;   // element offset, %4==0 -> 8B aligned
            short4_t lo = *(const short4_t*)(emb + e);
            short4_t hi = *(const short4_t*)(emb + e + 4);
            short8_t f8;
            f8[0] = lo[0]; f8[1] = lo[1]; f8[2] = lo[2]; f8[3] = lo[3];
            f8[4] = hi[0]; f8[5] = hi[1]; f8[6] = hi[2]; f8[7] = hi[3];
            afrag[tm2][kt] = f8;
        }
    }

    // ---- main loop over n-tiles ----
    for (int nt = 0; nt < NNT; ++nt) {
        // B fragments: fragment-linear, fully coalesced dwordx4 loads
        const short8_t* bpv = (const short8_t*)(bp) + (nt * NKT) * 64;
        short8_t bfrag[NKT];
        #pragma unroll
        for (int kt = 0; kt < NKT; ++kt) bfrag[kt] = bpv[kt * 64 + lane];

        int f = nt * 16 + (lane & 15);
        float bias = (f < FF) ? convb[f] : 0.0f;

        float4_t acc0 = {0.f, 0.f, 0.f, 0.f};
        float4_t acc1 = {0.f, 0.f, 0.f, 0.f};
        #pragma unroll
        for (int kt = 0; kt < NKT; ++kt) {
            acc0 = __builtin_amdgcn_mfma_f32_16x16x32_bf16(afrag[0][kt], bfrag[kt], acc0, 0, 0, 0);
            acc1 = __builtin_amdgcn_mfma_f32_16x16x32_bf16(afrag[1][kt], bfrag[kt], acc1, 0, 0, 0);
        }

        // ---- tanh + segment max.  C layout: col=lane&15 (f), row=(lane>>4)*4+reg (l) ----
        float mx0 = -INFINITY, mx1 = -INFINITY, mx2 = -INFINITY;
        #pragma unroll
        for (int tm2 = 0; tm2 < 2; ++tm2) {
            int rowb = wid * 32 + tm2 * 16 + (lane >> 4) * 4;
            float4_t acc = tm2 ? acc1 : acc0;
            #pragma unroll
            for (int r = 0; r < 4; ++r) {
                int l = rowb + r;
                if (l < LL) {
                    float y = tanh_fast(acc[r] + bias);
                    int seg = (l >= pool0) + (l >= pool1);
                    if (seg == 0)      mx0 = fmaxf(mx0, y);
                    else if (seg == 1) mx1 = fmaxf(mx1, y);
                    else               mx2 = fmaxf(mx2, y);
                }
            }
        }
        // reduce over the 4 row-groups (lane bits 4,5); col (f) preserved
        mx0 = fmaxf(mx0, __shfl_xor(mx0, 16)); mx0 = fmaxf(mx0, __shfl_xor(mx0, 32));
        mx1 = fmaxf(mx1, __shfl_xor(mx1, 16)); mx1 = fmaxf(mx1, __shfl_xor(mx1, 32));
        mx2 = fmaxf(mx2, __shfl_xor(mx2, 16)); mx2 = fmaxf(mx2, __shfl_xor(mx2, 32));
        if (lane < 16) {
            partial[(wid * NPAD + nt * 16 + lane) * 3 + 0] = mx0;
            partial[(wid * NPAD + nt * 16 + lane) * 3 + 1] = mx1;
            partial[(wid * NPAD + nt * 16 + lane) * 3 + 2] = mx2;
        }
    }
    __syncthreads();

    // ---- combine wave partials: feats[f*3+s] ----
    for (int i = tid; i < NPAD * 3; i += 256) {
        float m = partial[0 * NPAD * 3 + i];
        m = fmaxf(m, partial[1 * NPAD * 3 + i]);
        m = fmaxf(m, partial[2 * NPAD * 3 + i]);
        m = fmaxf(m, partial[3 * NPAD * 3 + i]);
        feats[i] = m;
    }
    __syncthreads();

    // ---- linear epilogue: out[b,r] = feats[0:690] . linw[r,:] + linb[r] ----
    if (tid < 4 * RR) {  // 212 threads: r = tid>>2, p = tid&3
        int r = tid >> 2;
        int p = tid & 3;
        float acc = 0.0f;
        for (int i = p; i < 3 * FF; i += 4) acc += feats[i] * linw[r * (3 * FF) + i];
        acc += __shfl_xor(acc, 1);
        acc += __shfl_xor(acc, 2);
        if (p == 0) out[b * RR + r] = acc + linb[r];
    }
}

extern "C" void kernel_launch(void* const* d_in, const int* in_sizes, int n_in,
                              void* d_out, int out_size, void* d_ws, size_t ws_size,
                              hipStream_t stream) {
    const int*   sent  = (const int*)d_in[0];
    const int*   pf    = (const int*)d_in[1];
    const int*   epos  = (const int*)d_in[2];
    const float* Wword = (const float*)d_in[3];
    const float* Wpos1 = (const float*)d_in[4];
    const float* Wpos2 = (const float*)d_in[5];
    const float* convw = (const float*)d_in[6];
    const float* convb = (const float*)d_in[7];
    const float* linw  = (const float*)d_in[8];
    const float* linb  = (const float*)d_in[9];
    float* out = (float*)d_out;
    unsigned short* bp = (unsigned short*)d_ws;   // 46080 bf16 = 92160 B

    int nprep = (NNT * NKT * 64 * 8 + 255) / 256;
    pcnn_prep_b<<<nprep, 256, 0, stream>>>(convw, bp);
    pcnn_mfma<<<BB, 256, 0, stream>>>(sent, pf, epos, Wword, Wpos1, Wpos2,
                                      bp, convb, linw, linb, out);
}